// Round 1
// baseline (376.521 us; speedup 1.0000x reference)
//
#include <hip/hip_runtime.h>

// HorizontalWidthTokenPyramid: x[n,c,s,16,16] f32 -> out[n,c,s,31,4] f32
// Per slice (n,c,s): for b in {16,8,4,2,1}: height bins of span 16/b reduced
// with mean+max -> z[b][16]; then width pooled to 4 tokens with mean+max.
//
// Mapping: one wave (64 lanes) per slice. lane = r*4 + g (r=row, g=token).
// Each lane loads float4 = x[r][4g..4g+3] (wave reads 1024 contiguous B).
// Hierarchical row reduction via __shfl_xor(4/8/16/32) builds per-column
// sum/max over spans 1,2,4,8,16. At each level every lane computes its
// token value; a masked lane subset writes consecutive output floats.

__global__ __launch_bounds__(256) void hwtp_kernel(const float* __restrict__ x,
                                                   float* __restrict__ out,
                                                   int num_slices) {
    const int gtid  = blockIdx.x * blockDim.x + threadIdx.x;
    const int slice = gtid >> 6;
    const int lane  = threadIdx.x & 63;
    if (slice >= num_slices) return;

    // lane r*4+g loads x[slice][r][4g..4g+3]
    const float4 v = reinterpret_cast<const float4*>(x)[(size_t)slice * 64 + lane];
    float* __restrict__ o = out + (size_t)slice * 124;

    const int g = lane & 3;

    // running per-column sum/max over the current row span
    float s0 = v.x, s1 = v.y, s2 = v.z, s3 = v.w;
    float m0 = v.x, m1 = v.y, m2 = v.z, m3 = v.w;

    // ---- level b=16 (span=1): z = x + x ----
    {
        float z0 = s0 + m0, z1 = s1 + m1, z2 = s2 + m2, z3 = s3 + m3;
        float val = 0.25f * ((z0 + z1) + (z2 + z3))
                  + fmaxf(fmaxf(z0, z1), fmaxf(z2, z3));
        o[lane] = val;  // 64 consecutive floats: bins 0..15 x tokens 0..3
    }

#define REDUCE(mask)                                                     \
    s0 += __shfl_xor(s0, mask); s1 += __shfl_xor(s1, mask);              \
    s2 += __shfl_xor(s2, mask); s3 += __shfl_xor(s3, mask);              \
    m0 = fmaxf(m0, __shfl_xor(m0, mask));                                \
    m1 = fmaxf(m1, __shfl_xor(m1, mask));                                \
    m2 = fmaxf(m2, __shfl_xor(m2, mask));                                \
    m3 = fmaxf(m3, __shfl_xor(m3, mask));

#define TOKEN_VAL(inv_span, dst)                                         \
    {                                                                    \
        float z0 = fmaf(s0, inv_span, m0);                               \
        float z1 = fmaf(s1, inv_span, m1);                               \
        float z2 = fmaf(s2, inv_span, m2);                               \
        float z3 = fmaf(s3, inv_span, m3);                               \
        dst = 0.25f * ((z0 + z1) + (z2 + z3))                            \
            + fmaxf(fmaxf(z0, z1), fmaxf(z2, z3));                       \
    }

    float val;

    // ---- level b=8 (span=2): rows {2j,2j+1} ----
    REDUCE(4)
    TOKEN_VAL(0.5f, val)
    if ((lane & 4) == 0)                       // r even; bin j = r>>1
        o[64 + ((lane >> 3) << 2) + g] = val;  // 32 consecutive floats

    // ---- level b=4 (span=4) ----
    REDUCE(8)
    TOKEN_VAL(0.25f, val)
    if ((lane & 12) == 0)                      // r % 4 == 0; bin = r>>2
        o[96 + ((lane >> 4) << 2) + g] = val;  // 16 consecutive floats

    // ---- level b=2 (span=8) ----
    REDUCE(16)
    TOKEN_VAL(0.125f, val)
    if ((lane & 28) == 0)                      // r % 8 == 0; bin = r>>3
        o[112 + ((lane >> 5) << 2) + g] = val; // 8 consecutive floats

    // ---- level b=1 (span=16) ----
    REDUCE(32)
    TOKEN_VAL(0.0625f, val)
    if (lane < 4)
        o[120 + g] = val;                      // 4 consecutive floats

#undef REDUCE
#undef TOKEN_VAL
}

extern "C" void kernel_launch(void* const* d_in, const int* in_sizes, int n_in,
                              void* d_out, int out_size, void* d_ws, size_t ws_size,
                              hipStream_t stream) {
    const float* x = (const float*)d_in[0];
    float* out = (float*)d_out;

    const int num_slices = in_sizes[0] / 256;       // n*c*s, 256 floats/slice
    const int block = 256;                          // 4 waves = 4 slices/block
    const int grid = (num_slices * 64 + block - 1) / block;

    hwtp_kernel<<<grid, block, 0, stream>>>(x, out, num_slices);
}